// Round 7
// baseline (447.567 us; speedup 1.0000x reference)
//
#include <hip/hip_runtime.h>
#include <math.h>

#define NN 50000
#define NE 800000
#define MUL 32
#define NPB 4       /* nodes per k_node block */
#define SCANB 49    /* ceil(NN/1024) */

static __device__ __forceinline__ float sigmoidf_(float v) {
    return 1.0f / (1.0f + __expf(-v));
}

#define INV_SQRT_MUL   0.17677669529663687f   /* 1/sqrt(32) */
#define INV_SQRT_NEMB  0.35355339059327373f   /* 1/sqrt(8)  */
#define INV_SQRT_HID   0.35355339059327373f   /* 1/sqrt(8)  */
#define INV3C          0.5773502691896258f    /* 1/sqrt(3)  */
#define INV2C          0.7071067811865476f    /* 1/sqrt(2)  */
#define INV_NEIGH      0.25f                  /* 1/sqrt(16) */
#define INV_SQRT_2MUL  0.125f                 /* 1/sqrt(64) */
#define INV_SQRT_3MUL  0.10206207261596575f   /* 1/sqrt(96) */
#define NSC            0.0625f                /* 1/sqrt(32*8) */

// ---------------------------------------------------------------------------
// K1 (unchanged): NPB=4 nodes/block, Wsc loaded once per block, fused dst
// histogram. x layout packed-per-u:
//   x[n*128 + 4*u + 0] = s[u],  x[n*128 + 4*u + 1 + c] = v[u][c]
// ---------------------------------------------------------------------------
__global__ __launch_bounds__(256) void k_node(
    const float* __restrict__ node_s, const float* __restrict__ node_v,
    const float* __restrict__ attrs,
    const float* __restrict__ W1_s, const float* __restrict__ W1_v,
    const float* __restrict__ Wsc_s, const float* __restrict__ Wsc_v,
    const int* __restrict__ edge_dst, int* __restrict__ counts,
    float* __restrict__ x, float* __restrict__ out)
{
    __shared__ float nd[NPB][136];
    __shared__ float gs[NPB][1024];
    __shared__ float gv[NPB][1024];
    const int t  = threadIdx.x;
    const int nb = blockIdx.x * NPB;

    {
        int g = blockIdx.x * 256 + t;
        if (g < NE) atomicAdd(&counts[edge_dst[g]], 1);
    }

#pragma unroll
    for (int i = t; i < NPB * 128; i += 256) {
        int nn = i >> 7, j = i & 127;
        nd[nn][j] = (j < 32) ? node_s[(nb + nn) * 32 + j]
                             : node_v[(nb + nn) * 96 + (j - 32)];
    }
    if (t < NPB * 8) nd[t >> 3][128 + (t & 7)] = attrs[(nb + (t >> 3)) * 8 + (t & 7)];
    __syncthreads();

    float at[NPB][8];
#pragma unroll
    for (int nn = 0; nn < NPB; ++nn)
#pragma unroll
        for (int a = 0; a < 8; ++a) at[nn][a] = nd[nn][128 + a];

#pragma unroll
    for (int r = 0; r < 4; ++r) {
        const int idx = t + 256 * r;
        const int u = idx >> 5, vch = idx & 31;
        float as[NPB] = {0.f, 0.f, 0.f, 0.f};
        float av[NPB] = {0.f, 0.f, 0.f, 0.f};
#pragma unroll
        for (int a = 0; a < 8; ++a) {
            const float ws = Wsc_s[(u * 8 + a) * 32 + vch];
            const float wvw = Wsc_v[(u * 8 + a) * 32 + vch];
#pragma unroll
            for (int nn = 0; nn < NPB; ++nn) {
                as[nn] += at[nn][a] * ws;
                av[nn] += at[nn][a] * wvw;
            }
        }
#pragma unroll
        for (int nn = 0; nn < NPB; ++nn) {
            gs[nn][idx] = as[nn];
            gv[nn][idx] = av[nn];
        }
    }
    __syncthreads();

    const int o  = t & 127;
    const int nh = t >> 7;
    if (o < 32) {
        float ax[2] = {0.f, 0.f}, asc[2] = {0.f, 0.f};
#pragma unroll
        for (int uu = 0; uu < 32; ++uu) {
            const float w1 = W1_s[uu * 32 + o];
#pragma unroll
            for (int r2 = 0; r2 < 2; ++r2) {
                const int nn = nh + 2 * r2;
                const float s = nd[nn][uu];
                ax[r2]  += s * w1;
                asc[r2] += s * gs[nn][(uu << 5) + o];
            }
        }
#pragma unroll
        for (int r2 = 0; r2 < 2; ++r2) {
            const int nidx = nb + nh + 2 * r2;
            x[(size_t)nidx * 128 + 4 * o] = ax[r2] * INV_SQRT_MUL;
            out[(size_t)nidx * 128 + o]   = asc[r2] * NSC;
        }
    } else {
        const int q = o - 32;
        const int vch = q / 3, c = q - 3 * vch;
        float ax[2] = {0.f, 0.f}, asc[2] = {0.f, 0.f};
#pragma unroll
        for (int uu = 0; uu < 32; ++uu) {
            const float w1 = W1_v[uu * 32 + vch];
#pragma unroll
            for (int r2 = 0; r2 < 2; ++r2) {
                const int nn = nh + 2 * r2;
                const float vv = nd[nn][32 + 3 * uu + c];
                ax[r2]  += vv * w1;
                asc[r2] += vv * gv[nn][(uu << 5) + vch];
            }
        }
#pragma unroll
        for (int r2 = 0; r2 < 2; ++r2) {
            const int nidx = nb + nh + 2 * r2;
            x[(size_t)nidx * 128 + 4 * vch + 1 + c] = ax[r2] * INV_SQRT_MUL;
            out[(size_t)nidx * 128 + o]             = asc[r2] * NSC;
        }
    }
}

// ---------------------------------------------------------------------------
// K3a: per-block exclusive scan (1024 elems/block) + block sums
// ---------------------------------------------------------------------------
__global__ __launch_bounds__(1024) void k_scan_a(
    const int* __restrict__ counts, int* __restrict__ escan,
    int* __restrict__ bsum)
{
    __shared__ int sh[1024];
    const int t = threadIdx.x;
    const int i = blockIdx.x * 1024 + t;
    int v = (i < NN) ? counts[i] : 0;
    sh[t] = v;
    __syncthreads();
    for (int off = 1; off < 1024; off <<= 1) {
        int u = (t >= off) ? sh[t - off] : 0;
        __syncthreads();
        sh[t] += u;
        __syncthreads();
    }
    if (i < NN) escan[i] = sh[t] - v;
    if (t == 1023) bsum[blockIdx.x] = sh[1023];
}

// ---------------------------------------------------------------------------
// K3c: per-block bsum prefix + add-back -> offsets[N+1], cursor[N]
// ---------------------------------------------------------------------------
__global__ __launch_bounds__(1024) void k_scan_c(
    const int* __restrict__ escan, const int* __restrict__ bsum,
    int* __restrict__ offsets, int* __restrict__ cursor)
{
    __shared__ int sbase;
    const int t = threadIdx.x;
    if (t < 64) {
        int v = (t < blockIdx.x) ? bsum[t] : 0;
        for (int off = 32; off > 0; off >>= 1) v += __shfl_xor(v, off, 64);
        if (t == 0) sbase = v;
    }
    __syncthreads();
    const int i = blockIdx.x * 1024 + t;
    if (i == 0) offsets[NN] = NE;
    if (i < NN) {
        int o = sbase + escan[i];
        offsets[i] = o;
        cursor[i] = o;
    }
}

// ---------------------------------------------------------------------------
// K4: pack — radial-MLP hidden h + 64B record at CSR position.
// record: [0]=src(bits) [1]=sh0 [2..4]=sh1 [5..12]=h [13..15]=pad
// ---------------------------------------------------------------------------
__global__ __launch_bounds__(256) void k_pack(
    const float* __restrict__ edge_emb, const float* __restrict__ edge_sh0,
    const float* __restrict__ edge_sh1,
    const int* __restrict__ edge_src, const int* __restrict__ edge_dst,
    const float* __restrict__ Wm1,
    int* __restrict__ cursor, float* __restrict__ epack)
{
    int e = blockIdx.x * 256 + threadIdx.x;
    if (e >= NE) return;
    const float4* p = (const float4*)(edge_emb + e * 8);
    float4 a = p[0], b = p[1];
    float emb[8] = {a.x, a.y, a.z, a.w, b.x, b.y, b.z, b.w};
    float h[8];
#pragma unroll
    for (int j = 0; j < 8; ++j) {
        float s = 0.f;
#pragma unroll
        for (int k = 0; k < 8; ++k) s += emb[k] * Wm1[k * 8 + j];
        s *= INV_SQRT_NEMB;
        h[j] = s * sigmoidf_(s);
    }
    float sh0 = edge_sh0[e];
    float sx = edge_sh1[3 * e], sy = edge_sh1[3 * e + 1], sz = edge_sh1[3 * e + 2];
    int src = edge_src[e];
    int pos = atomicAdd(&cursor[edge_dst[e]], 1);
    float4* op = (float4*)(epack + (size_t)pos * 16);
    op[0] = make_float4(__int_as_float(src), sh0, sx, sy);
    op[1] = make_float4(sz, h[0], h[1], h[2]);
    op[2] = make_float4(h[3], h[4], h[5], h[6]);
    op[3] = make_float4(h[7], 0.f, 0.f, 0.f);
}

// ---------------------------------------------------------------------------
// K5 (v10): v9 structure with two changes:
// (1) DEPTH-2 record pipeline: hold records for pairs it and it+1 in regs;
//     at iter it issue record it+2 and the x-row for it+1 (whose record
//     landed a full iteration ago) -> the record->x dependent chain no
//     longer serializes inside one iteration. Clamped-pointer addressing
//     keeps every read in [beg, end-1]; odd tail masked via sh=0 on half 1.
// (2) msg_v stored as float4 planes [96][4] -> v-fold reads one
//     ds_read_b128 per uu instead of 3 scalar LDS reads (672->480 instr).
// __launch_bounds__(256,3): room for the ~120-reg pipeline, no spills.
// ---------------------------------------------------------------------------
__global__ __launch_bounds__(256, 3) void k_gather(
    const float* __restrict__ x, const float* __restrict__ epack,
    const float* __restrict__ Wm2, const float* __restrict__ W2_s,
    const float* __restrict__ W2_v,
    const int* __restrict__ offsets, float* __restrict__ out)
{
    // per node: [0..31]=p1, [32..63]=p2, then 96 float4 vector slots
    // [64 + 4*uu .. +2], uu = (path-3)*32 + u. 452-float node stride ->
    // node groups offset by 4 banks (no fold conflicts), 16B-aligned.
    __shared__ __align__(16) float msg[4][452];

    const int w    = threadIdx.x >> 6;       // wave id = node within block
    const int L    = threadIdx.x & 63;
    const int u    = L & 31;
    const int half = L >> 5;
    const int n    = blockIdx.x * 4 + w;     // NN = 50000 = 12500*4, always valid

    // per-lane Wm2 columns for ALL 5 paths (role-independent), pre-scaled
    float wc[5][8];
#pragma unroll
    for (int p = 0; p < 5; ++p)
#pragma unroll
        for (int q = 0; q < 8; ++q)
            wc[p][q] = Wm2[q * 160 + p * 32 + u] * INV_SQRT_HID;

    float pa = 0.f, pb = 0.f;
    float p30 = 0.f, p31 = 0.f, p32 = 0.f;
    float p40 = 0.f, p41 = 0.f, p42 = 0.f;
    float p50 = 0.f, p51 = 0.f, p52 = 0.f;

    const int beg = offsets[n];
    const int end = offsets[n + 1];
    const int cnt = end - beg;

#define EDGE_BODY() do { \
        const float sh0 = r0.y, sx = r0.z, sy = r0.w, sz = r1.x; \
        const float w0 = r1.y*wc[0][0] + r1.z*wc[0][1] + r1.w*wc[0][2] + r2.x*wc[0][3] \
                       + r2.y*wc[0][4] + r2.z*wc[0][5] + r2.w*wc[0][6] + h7*wc[0][7]; \
        const float w1 = r1.y*wc[1][0] + r1.z*wc[1][1] + r1.w*wc[1][2] + r2.x*wc[1][3] \
                       + r2.y*wc[1][4] + r2.z*wc[1][5] + r2.w*wc[1][6] + h7*wc[1][7]; \
        const float w2 = r1.y*wc[2][0] + r1.z*wc[2][1] + r1.w*wc[2][2] + r2.x*wc[2][3] \
                       + r2.y*wc[2][4] + r2.z*wc[2][5] + r2.w*wc[2][6] + h7*wc[2][7]; \
        const float w3 = r1.y*wc[3][0] + r1.z*wc[3][1] + r1.w*wc[3][2] + r2.x*wc[3][3] \
                       + r2.y*wc[3][4] + r2.z*wc[3][5] + r2.w*wc[3][6] + h7*wc[3][7]; \
        const float w4 = r1.y*wc[4][0] + r1.z*wc[4][1] + r1.w*wc[4][2] + r2.x*wc[4][3] \
                       + r2.y*wc[4][4] + r2.z*wc[4][5] + r2.w*wc[4][6] + h7*wc[4][7]; \
        const float ls = xv.x, lv0 = xv.y, lv1 = xv.z, lv2 = xv.w; \
        pa += w0 * (ls * sh0); \
        pb += w1 * (lv0 * sx + lv1 * sy + lv2 * sz); \
        const float t2 = w2 * ls; \
        p30 += t2 * sx; p31 += t2 * sy; p32 += t2 * sz; \
        const float t3 = w3 * sh0; \
        p40 += t3 * lv0; p41 += t3 * lv1; p42 += t3 * lv2; \
        p50 += w4 * (lv1 * sz - lv2 * sy); \
        p51 += w4 * (lv2 * sx - lv0 * sz); \
        p52 += w4 * (lv0 * sy - lv1 * sx); \
    } while (0)

    if (cnt > 0) {
        const int np = cnt >> 1;                           // full pairs
        const float* rl = epack + (size_t)(end - 1) * 16;  // last record
        const float* rb = epack + ((size_t)beg + half) * 16;
        if (rb > rl) rb = rl;                              // only cnt==1, half==1

        // pipeline prologue: records for pair 0 (r*) and pair 1 (n*)
        const float* pB = (rb + 32 <= rl) ? (rb + 32) : rl;
        float4 r0 = ((const float4*)rb)[0];
        float4 r1 = ((const float4*)rb)[1];
        float4 r2 = ((const float4*)rb)[2];
        float  h7 = rb[12];
        float4 n0 = ((const float4*)pB)[0];
        float4 n1 = ((const float4*)pB)[1];
        float4 n2 = ((const float4*)pB)[2];
        float  nh7 = pB[12];
        float4 xv = *(const float4*)(x + (size_t)__float_as_int(r0.x) * 128 + 4 * u);

        for (int it = 0; it < np; ++it) {
            // issue record it+2 (clamped) and x-row for pair it+1
            const float* pC = (rb + (size_t)(it + 2) * 32 <= rl)
                              ? (rb + (size_t)(it + 2) * 32) : rl;
            const float4 f0 = ((const float4*)pC)[0];
            const float4 f1 = ((const float4*)pC)[1];
            const float4 f2 = ((const float4*)pC)[2];
            const float  fh7 = pC[12];
            const float4 nxv = *(const float4*)(x + (size_t)__float_as_int(n0.x) * 128 + 4 * u);

            EDGE_BODY();

            r0 = n0; r1 = n1; r2 = n2; h7 = nh7;
            n0 = f0; n1 = f1; n2 = f2; nh7 = fh7;
            xv = nxv;
        }
        if (cnt & 1) {
            // r* now holds record end-1 for both halves; xv its x-row.
            // zero sh for half 1 (all paths linear in sh)
            const float mask = (half == 0) ? 1.f : 0.f;
            r0.y *= mask; r0.z *= mask; r0.w *= mask; r1.x *= mask;
            EDGE_BODY();
        }
    }
#undef EDGE_BODY

    // combine even/odd-edge partials across halves
    pa  += __shfl_xor(pa, 32);  pb  += __shfl_xor(pb, 32);
    p30 += __shfl_xor(p30, 32); p31 += __shfl_xor(p31, 32); p32 += __shfl_xor(p32, 32);
    p40 += __shfl_xor(p40, 32); p41 += __shfl_xor(p41, 32); p42 += __shfl_xor(p42, 32);
    p50 += __shfl_xor(p50, 32); p51 += __shfl_xor(p51, 32); p52 += __shfl_xor(p52, 32);

    {
        float* mg = msg[w];
        if (half == 0) {
            mg[u]      = pa * INV_NEIGH;
            mg[32 + u] = pb * (INV3C * INV_NEIGH);
            *(float4*)&mg[64 + 4 * u] =
                make_float4(p30 * INV_NEIGH, p31 * INV_NEIGH, p32 * INV_NEIGH, 0.f);
        } else {
            *(float4*)&mg[64 + 4 * (32 + u)] =
                make_float4(p40 * INV_NEIGH, p41 * INV_NEIGH, p42 * INV_NEIGH, 0.f);
            const float f = INV2C * INV_NEIGH;
            *(float4*)&mg[64 + 4 * (64 + u)] =
                make_float4(p50 * f, p51 * f, p52 * f, 0.f);
        }
    }
    __syncthreads();

    // divergence-free cooperative fold of linear_2 for the block's 4 nodes;
    // W2 read directly from global (20KB, coalesced + repeating -> L1)
    {
        const int nb = blockIdx.x * 4;
        const int t = threadIdx.x;
        if (t < 128) {
            const int node = t >> 5, o = t & 31;
            float s = 0.f;
#pragma unroll 16
            for (int uu = 0; uu < 64; ++uu) s += msg[node][uu] * W2_s[uu * 32 + o];
            out[(size_t)(nb + node) * 128 + o] += s * INV_SQRT_2MUL;
        } else {
            const int node = (t - 128) >> 5, vch = t & 31;
            float s0 = 0.f, s1 = 0.f, s2 = 0.f;
#pragma unroll 8
            for (int uu = 0; uu < 96; ++uu) {
                const float wgt = W2_v[uu * 32 + vch];
                const float4 mv = *(const float4*)&msg[node][64 + 4 * uu];
                s0 += mv.x * wgt;
                s1 += mv.y * wgt;
                s2 += mv.z * wgt;
            }
            float* po = out + (size_t)(nb + node) * 128 + 32 + vch * 3;
            po[0] += s0 * INV_SQRT_3MUL;
            po[1] += s1 * INV_SQRT_3MUL;
            po[2] += s2 * INV_SQRT_3MUL;
        }
    }
}

// ---------------------------------------------------------------------------
extern "C" void kernel_launch(void* const* d_in, const int* in_sizes, int n_in,
                              void* d_out, int out_size, void* d_ws, size_t ws_size,
                              hipStream_t stream) {
    const float* node_s   = (const float*)d_in[0];
    const float* node_v   = (const float*)d_in[1];
    const float* attrs    = (const float*)d_in[2];
    const float* edge_emb = (const float*)d_in[3];
    const float* edge_sh0 = (const float*)d_in[4];
    const float* edge_sh1 = (const float*)d_in[5];
    const float* W1_s     = (const float*)d_in[6];
    const float* W1_v     = (const float*)d_in[7];
    const float* Wm1      = (const float*)d_in[8];
    const float* Wm2      = (const float*)d_in[9];
    const float* W2_s     = (const float*)d_in[10];
    const float* W2_v     = (const float*)d_in[11];
    const float* Wsc_s    = (const float*)d_in[12];
    const float* Wsc_v    = (const float*)d_in[13];
    const int*   edge_src = (const int*)d_in[14];
    const int*   edge_dst = (const int*)d_in[15];
    float* out = (float*)d_out;

    // workspace layout (unchanged)
    float* x     = (float*)d_ws;                     // N*128
    float* epack = x + (size_t)NN * 128;             // E*16
    int*   counts  = (int*)(epack + (size_t)NE * 16);// N
    int*   offsets = counts + NN;                    // N+1
    int*   cursor  = offsets + NN + 1;               // N
    int*   escan   = cursor + NN;                    // N
    int*   bsum    = escan + NN;                     // SCANB

    hipMemsetAsync(counts, 0, NN * sizeof(int), stream);

    k_node<<<NN / NPB, 256, 0, stream>>>(node_s, node_v, attrs,
                                         W1_s, W1_v, Wsc_s, Wsc_v,
                                         edge_dst, counts, x, out);
    k_scan_a<<<SCANB, 1024, 0, stream>>>(counts, escan, bsum);
    k_scan_c<<<SCANB, 1024, 0, stream>>>(escan, bsum, offsets, cursor);
    k_pack<<<(NE + 255) / 256, 256, 0, stream>>>(edge_emb, edge_sh0, edge_sh1,
                                                 edge_src, edge_dst, Wm1,
                                                 cursor, epack);
    k_gather<<<NN / 4, 256, 0, stream>>>(x, epack, Wm2, W2_s, W2_v,
                                         offsets, out);
}

// Round 8
// 398.030 us; speedup vs baseline: 1.1245x; 1.1245x over previous
//
#include <hip/hip_runtime.h>
#include <math.h>

#define NN 50000
#define NE 800000
#define MUL 32
#define NPB 4       /* nodes per k_node block */
#define SCANB 49    /* ceil(NN/1024) */

static __device__ __forceinline__ float sigmoidf_(float v) {
    return 1.0f / (1.0f + __expf(-v));
}

typedef float f32x2 __attribute__((ext_vector_type(2)));

#define INV_SQRT_MUL   0.17677669529663687f   /* 1/sqrt(32) */
#define INV_SQRT_NEMB  0.35355339059327373f   /* 1/sqrt(8)  */
#define INV_SQRT_HID   0.35355339059327373f   /* 1/sqrt(8)  */
#define INV3C          0.5773502691896258f    /* 1/sqrt(3)  */
#define INV2C          0.7071067811865476f    /* 1/sqrt(2)  */
#define INV_NEIGH      0.25f                  /* 1/sqrt(16) */
#define INV_SQRT_2MUL  0.125f                 /* 1/sqrt(64) */
#define INV_SQRT_3MUL  0.10206207261596575f   /* 1/sqrt(96) */
#define NSC            0.0625f                /* 1/sqrt(32*8) */

// ---------------------------------------------------------------------------
// K1 (unchanged): NPB=4 nodes/block, Wsc loaded once per block, fused dst
// histogram. x layout packed-per-u:
//   x[n*128 + 4*u + 0] = s[u],  x[n*128 + 4*u + 1 + c] = v[u][c]
// ---------------------------------------------------------------------------
__global__ __launch_bounds__(256) void k_node(
    const float* __restrict__ node_s, const float* __restrict__ node_v,
    const float* __restrict__ attrs,
    const float* __restrict__ W1_s, const float* __restrict__ W1_v,
    const float* __restrict__ Wsc_s, const float* __restrict__ Wsc_v,
    const int* __restrict__ edge_dst, int* __restrict__ counts,
    float* __restrict__ x, float* __restrict__ out)
{
    __shared__ float nd[NPB][136];
    __shared__ float gs[NPB][1024];
    __shared__ float gv[NPB][1024];
    const int t  = threadIdx.x;
    const int nb = blockIdx.x * NPB;

    {
        int g = blockIdx.x * 256 + t;
        if (g < NE) atomicAdd(&counts[edge_dst[g]], 1);
    }

#pragma unroll
    for (int i = t; i < NPB * 128; i += 256) {
        int nn = i >> 7, j = i & 127;
        nd[nn][j] = (j < 32) ? node_s[(nb + nn) * 32 + j]
                             : node_v[(nb + nn) * 96 + (j - 32)];
    }
    if (t < NPB * 8) nd[t >> 3][128 + (t & 7)] = attrs[(nb + (t >> 3)) * 8 + (t & 7)];
    __syncthreads();

    float at[NPB][8];
#pragma unroll
    for (int nn = 0; nn < NPB; ++nn)
#pragma unroll
        for (int a = 0; a < 8; ++a) at[nn][a] = nd[nn][128 + a];

#pragma unroll
    for (int r = 0; r < 4; ++r) {
        const int idx = t + 256 * r;
        const int u = idx >> 5, vch = idx & 31;
        float as[NPB] = {0.f, 0.f, 0.f, 0.f};
        float av[NPB] = {0.f, 0.f, 0.f, 0.f};
#pragma unroll
        for (int a = 0; a < 8; ++a) {
            const float ws = Wsc_s[(u * 8 + a) * 32 + vch];
            const float wvw = Wsc_v[(u * 8 + a) * 32 + vch];
#pragma unroll
            for (int nn = 0; nn < NPB; ++nn) {
                as[nn] += at[nn][a] * ws;
                av[nn] += at[nn][a] * wvw;
            }
        }
#pragma unroll
        for (int nn = 0; nn < NPB; ++nn) {
            gs[nn][idx] = as[nn];
            gv[nn][idx] = av[nn];
        }
    }
    __syncthreads();

    const int o  = t & 127;
    const int nh = t >> 7;
    if (o < 32) {
        float ax[2] = {0.f, 0.f}, asc[2] = {0.f, 0.f};
#pragma unroll
        for (int uu = 0; uu < 32; ++uu) {
            const float w1 = W1_s[uu * 32 + o];
#pragma unroll
            for (int r2 = 0; r2 < 2; ++r2) {
                const int nn = nh + 2 * r2;
                const float s = nd[nn][uu];
                ax[r2]  += s * w1;
                asc[r2] += s * gs[nn][(uu << 5) + o];
            }
        }
#pragma unroll
        for (int r2 = 0; r2 < 2; ++r2) {
            const int nidx = nb + nh + 2 * r2;
            x[(size_t)nidx * 128 + 4 * o] = ax[r2] * INV_SQRT_MUL;
            out[(size_t)nidx * 128 + o]   = asc[r2] * NSC;
        }
    } else {
        const int q = o - 32;
        const int vch = q / 3, c = q - 3 * vch;
        float ax[2] = {0.f, 0.f}, asc[2] = {0.f, 0.f};
#pragma unroll
        for (int uu = 0; uu < 32; ++uu) {
            const float w1 = W1_v[uu * 32 + vch];
#pragma unroll
            for (int r2 = 0; r2 < 2; ++r2) {
                const int nn = nh + 2 * r2;
                const float vv = nd[nn][32 + 3 * uu + c];
                ax[r2]  += vv * w1;
                asc[r2] += vv * gv[nn][(uu << 5) + vch];
            }
        }
#pragma unroll
        for (int r2 = 0; r2 < 2; ++r2) {
            const int nidx = nb + nh + 2 * r2;
            x[(size_t)nidx * 128 + 4 * vch + 1 + c] = ax[r2] * INV_SQRT_MUL;
            out[(size_t)nidx * 128 + o]             = asc[r2] * NSC;
        }
    }
}

// ---------------------------------------------------------------------------
// K3a: per-block exclusive scan (1024 elems/block) + block sums
// ---------------------------------------------------------------------------
__global__ __launch_bounds__(1024) void k_scan_a(
    const int* __restrict__ counts, int* __restrict__ escan,
    int* __restrict__ bsum)
{
    __shared__ int sh[1024];
    const int t = threadIdx.x;
    const int i = blockIdx.x * 1024 + t;
    int v = (i < NN) ? counts[i] : 0;
    sh[t] = v;
    __syncthreads();
    for (int off = 1; off < 1024; off <<= 1) {
        int u = (t >= off) ? sh[t - off] : 0;
        __syncthreads();
        sh[t] += u;
        __syncthreads();
    }
    if (i < NN) escan[i] = sh[t] - v;
    if (t == 1023) bsum[blockIdx.x] = sh[1023];
}

// ---------------------------------------------------------------------------
// K3c: per-block bsum prefix + add-back -> offsets[N+1], cursor[N]
// ---------------------------------------------------------------------------
__global__ __launch_bounds__(1024) void k_scan_c(
    const int* __restrict__ escan, const int* __restrict__ bsum,
    int* __restrict__ offsets, int* __restrict__ cursor)
{
    __shared__ int sbase;
    const int t = threadIdx.x;
    if (t < 64) {
        int v = (t < blockIdx.x) ? bsum[t] : 0;
        for (int off = 32; off > 0; off >>= 1) v += __shfl_xor(v, off, 64);
        if (t == 0) sbase = v;
    }
    __syncthreads();
    const int i = blockIdx.x * 1024 + t;
    if (i == 0) offsets[NN] = NE;
    if (i < NN) {
        int o = sbase + escan[i];
        offsets[i] = o;
        cursor[i] = o;
    }
}

// ---------------------------------------------------------------------------
// K4: pack — radial-MLP hidden h + 64B record at CSR position.
// record: [0]=src(bits) [1]=sh0 [2..4]=sh1 [5..12]=h [13..15]=pad
// ---------------------------------------------------------------------------
__global__ __launch_bounds__(256) void k_pack(
    const float* __restrict__ edge_emb, const float* __restrict__ edge_sh0,
    const float* __restrict__ edge_sh1,
    const int* __restrict__ edge_src, const int* __restrict__ edge_dst,
    const float* __restrict__ Wm1,
    int* __restrict__ cursor, float* __restrict__ epack)
{
    int e = blockIdx.x * 256 + threadIdx.x;
    if (e >= NE) return;
    const float4* p = (const float4*)(edge_emb + e * 8);
    float4 a = p[0], b = p[1];
    float emb[8] = {a.x, a.y, a.z, a.w, b.x, b.y, b.z, b.w};
    float h[8];
#pragma unroll
    for (int j = 0; j < 8; ++j) {
        float s = 0.f;
#pragma unroll
        for (int k = 0; k < 8; ++k) s += emb[k] * Wm1[k * 8 + j];
        s *= INV_SQRT_NEMB;
        h[j] = s * sigmoidf_(s);
    }
    float sh0 = edge_sh0[e];
    float sx = edge_sh1[3 * e], sy = edge_sh1[3 * e + 1], sz = edge_sh1[3 * e + 2];
    int src = edge_src[e];
    int pos = atomicAdd(&cursor[edge_dst[e]], 1);
    float4* op = (float4*)(epack + (size_t)pos * 16);
    op[0] = make_float4(__int_as_float(src), sh0, sx, sy);
    op[1] = make_float4(sz, h[0], h[1], h[2]);
    op[2] = make_float4(h[3], h[4], h[5], h[6]);
    op[3] = make_float4(h[7], 0.f, 0.f, 0.f);
}

// ---------------------------------------------------------------------------
// K5 (v11): EXACT v8 structure (best measured: 146 µs) with ONE change —
// the 5 per-edge w-dots are computed as packed float2 FMAs
// (v_pk_fma_f32 via __builtin_elementwise_fma on ext_vector float2):
// (w0,w1) and (w2,w3) packed, w4 scalar -> 40 scalar FMA -> 16 pk + 8 scalar
// per edge. Everything else byte-identical to v8.
// ---------------------------------------------------------------------------
__global__ __launch_bounds__(256) void k_gather(
    const float* __restrict__ x, const float* __restrict__ epack,
    const float* __restrict__ Wm2, const float* __restrict__ W2_s,
    const float* __restrict__ W2_v,
    const int* __restrict__ offsets, float* __restrict__ out)
{
    __shared__ float msg[4][360];               // per-wave message, padded

    const int w    = threadIdx.x >> 6;       // wave id = node within block
    const int L    = threadIdx.x & 63;
    const int u    = L & 31;
    const int half = L >> 5;
    const int n    = blockIdx.x * 4 + w;     // NN = 50000 = 12500*4, always valid

    // per-lane Wm2 columns, packed: wc01[q] = (path0, path1), wc23 = (2,3),
    // wc4 scalar; all pre-scaled by INV_SQRT_HID.
    f32x2 wc01[8], wc23[8];
    float wc4[8];
#pragma unroll
    for (int q = 0; q < 8; ++q) {
        wc01[q].x = Wm2[q * 160 +   0 + u] * INV_SQRT_HID;
        wc01[q].y = Wm2[q * 160 +  32 + u] * INV_SQRT_HID;
        wc23[q].x = Wm2[q * 160 +  64 + u] * INV_SQRT_HID;
        wc23[q].y = Wm2[q * 160 +  96 + u] * INV_SQRT_HID;
        wc4[q]    = Wm2[q * 160 + 128 + u] * INV_SQRT_HID;
    }

    float pa = 0.f, pb = 0.f;
    float p30 = 0.f, p31 = 0.f, p32 = 0.f;
    float p40 = 0.f, p41 = 0.f, p42 = 0.f;
    float p50 = 0.f, p51 = 0.f, p52 = 0.f;

    const int beg = offsets[n];
    const int end = offsets[n + 1];
    const int cnt = end - beg;

#define EDGE_BODY() do { \
        const float sh0 = r0.y, sx = r0.z, sy = r0.w, sz = r1.x; \
        const float hq0 = r1.y, hq1 = r1.z, hq2 = r1.w, hq3 = r2.x; \
        const float hq4 = r2.y, hq5 = r2.z, hq6 = r2.w, hq7 = h7; \
        f32x2 w01 = {0.f, 0.f}, w23 = {0.f, 0.f}; \
        w01 = __builtin_elementwise_fma((f32x2){hq0, hq0}, wc01[0], w01); \
        w23 = __builtin_elementwise_fma((f32x2){hq0, hq0}, wc23[0], w23); \
        w01 = __builtin_elementwise_fma((f32x2){hq1, hq1}, wc01[1], w01); \
        w23 = __builtin_elementwise_fma((f32x2){hq1, hq1}, wc23[1], w23); \
        w01 = __builtin_elementwise_fma((f32x2){hq2, hq2}, wc01[2], w01); \
        w23 = __builtin_elementwise_fma((f32x2){hq2, hq2}, wc23[2], w23); \
        w01 = __builtin_elementwise_fma((f32x2){hq3, hq3}, wc01[3], w01); \
        w23 = __builtin_elementwise_fma((f32x2){hq3, hq3}, wc23[3], w23); \
        w01 = __builtin_elementwise_fma((f32x2){hq4, hq4}, wc01[4], w01); \
        w23 = __builtin_elementwise_fma((f32x2){hq4, hq4}, wc23[4], w23); \
        w01 = __builtin_elementwise_fma((f32x2){hq5, hq5}, wc01[5], w01); \
        w23 = __builtin_elementwise_fma((f32x2){hq5, hq5}, wc23[5], w23); \
        w01 = __builtin_elementwise_fma((f32x2){hq6, hq6}, wc01[6], w01); \
        w23 = __builtin_elementwise_fma((f32x2){hq6, hq6}, wc23[6], w23); \
        w01 = __builtin_elementwise_fma((f32x2){hq7, hq7}, wc01[7], w01); \
        w23 = __builtin_elementwise_fma((f32x2){hq7, hq7}, wc23[7], w23); \
        const float w4 = hq0*wc4[0] + hq1*wc4[1] + hq2*wc4[2] + hq3*wc4[3] \
                       + hq4*wc4[4] + hq5*wc4[5] + hq6*wc4[6] + hq7*wc4[7]; \
        const float w0 = w01.x, w1 = w01.y, w2 = w23.x, w3 = w23.y; \
        const float ls = xv.x, lv0 = xv.y, lv1 = xv.z, lv2 = xv.w; \
        pa += w0 * (ls * sh0); \
        pb += w1 * (lv0 * sx + lv1 * sy + lv2 * sz); \
        const float t2 = w2 * ls; \
        p30 += t2 * sx; p31 += t2 * sy; p32 += t2 * sz; \
        const float t3 = w3 * sh0; \
        p40 += t3 * lv0; p41 += t3 * lv1; p42 += t3 * lv2; \
        p50 += w4 * (lv1 * sz - lv2 * sy); \
        p51 += w4 * (lv2 * sx - lv0 * sz); \
        p52 += w4 * (lv0 * sy - lv1 * sx); \
    } while (0)

#define PREFETCH(ptr) \
        const float4 q0 = ((const float4*)(ptr))[0]; \
        const float4 q1 = ((const float4*)(ptr))[1]; \
        const float4 q2 = ((const float4*)(ptr))[2]; \
        const float  qh7 = (ptr)[12]; \
        const float4 nxv = *(const float4*)(x + (size_t)__float_as_int(q0.x) * 128 + 4 * u)

#define ROTATE() do { r0 = q0; r1 = q1; r2 = q2; h7 = qh7; xv = nxv; } while (0)

    if (cnt > 0) {
        const int np = cnt >> 1;                       // full pairs
        const float* rl = epack + (size_t)(end - 1) * 16;  // last record
        const float* r  = epack + ((size_t)beg + half) * 16;
        if (r > rl) r = rl;                            // only when cnt==1, half==1
        float4 r0 = ((const float4*)r)[0];
        float4 r1 = ((const float4*)r)[1];
        float4 r2 = ((const float4*)r)[2];
        float  h7 = r[12];
        float4 xv = *(const float4*)(x + (size_t)__float_as_int(r0.x) * 128 + 4 * u);

        // steady state: prefetch r+2 records, provably < end
        for (int it = 0; it < np - 1; ++it) {
            r += 32;
            PREFETCH(r);
            EDGE_BODY();
            ROTATE();
        }

        if (np > 0) {
            if (cnt & 1) {
                // last full pair, prefetching the (uniform) tail record
                {
                    PREFETCH(rl);
                    EDGE_BODY();
                    ROTATE();
                }
                // tail edge: half 0 real, half 1 zeroed via sh mask
                const float mask = (half == 0) ? 1.f : 0.f;
                r0.y *= mask; r0.z *= mask; r0.w *= mask; r1.x *= mask;
                EDGE_BODY();
            } else {
                EDGE_BODY();
            }
        } else {
            // cnt == 1: both halves hold record end-1; mask half 1
            const float mask = (half == 0) ? 1.f : 0.f;
            r0.y *= mask; r0.z *= mask; r0.w *= mask; r1.x *= mask;
            EDGE_BODY();
        }
    }
#undef EDGE_BODY
#undef PREFETCH
#undef ROTATE

    // combine even/odd-edge partials across halves
    pa  += __shfl_xor(pa, 32);  pb  += __shfl_xor(pb, 32);
    p30 += __shfl_xor(p30, 32); p31 += __shfl_xor(p31, 32); p32 += __shfl_xor(p32, 32);
    p40 += __shfl_xor(p40, 32); p41 += __shfl_xor(p41, 32); p42 += __shfl_xor(p42, 32);
    p50 += __shfl_xor(p50, 32); p51 += __shfl_xor(p51, 32); p52 += __shfl_xor(p52, 32);

    // msg layout: [0..31]=p1, [32..63]=p2, vectors c-major: [64 + c*96 + uu],
    // uu = (path-3)*32 + u
    {
        float* mg = msg[w];
        if (half == 0) {
            mg[u]              = pa  * INV_NEIGH;
            mg[32 + u]         = pb  * (INV3C * INV_NEIGH);
            mg[64 + u]         = p30 * INV_NEIGH;
            mg[64 + 96 + u]    = p31 * INV_NEIGH;
            mg[64 + 192 + u]   = p32 * INV_NEIGH;
        } else {
            mg[64 + 32 + u]        = p40 * INV_NEIGH;
            mg[64 + 96 + 32 + u]   = p41 * INV_NEIGH;
            mg[64 + 192 + 32 + u]  = p42 * INV_NEIGH;
            const float f = INV2C * INV_NEIGH;
            mg[64 + 64 + u]        = p50 * f;
            mg[64 + 96 + 64 + u]   = p51 * f;
            mg[64 + 192 + 64 + u]  = p52 * f;
        }
    }
    __syncthreads();

    // divergence-free cooperative fold of linear_2 for the block's 4 nodes;
    // W2 read directly from global (L1-resident: 20KB, coalesced, repeating)
    {
        const int nb = blockIdx.x * 4;
        const int t = threadIdx.x;
        if (t < 128) {
            const int node = t >> 5, o = t & 31;
            float s = 0.f;
#pragma unroll
            for (int uu = 0; uu < 64; ++uu) s += msg[node][uu] * W2_s[uu * 32 + o];
            out[(size_t)(nb + node) * 128 + o] += s * INV_SQRT_2MUL;
        } else {
            const int node = (t - 128) >> 5, vch = t & 31;
            float s0 = 0.f, s1 = 0.f, s2 = 0.f;
#pragma unroll
            for (int uu = 0; uu < 96; ++uu) {
                const float wgt = W2_v[uu * 32 + vch];
                s0 += msg[node][64 + uu]       * wgt;
                s1 += msg[node][64 + 96 + uu]  * wgt;
                s2 += msg[node][64 + 192 + uu] * wgt;
            }
            float* po = out + (size_t)(nb + node) * 128 + 32 + vch * 3;
            po[0] += s0 * INV_SQRT_3MUL;
            po[1] += s1 * INV_SQRT_3MUL;
            po[2] += s2 * INV_SQRT_3MUL;
        }
    }
}

// ---------------------------------------------------------------------------
extern "C" void kernel_launch(void* const* d_in, const int* in_sizes, int n_in,
                              void* d_out, int out_size, void* d_ws, size_t ws_size,
                              hipStream_t stream) {
    const float* node_s   = (const float*)d_in[0];
    const float* node_v   = (const float*)d_in[1];
    const float* attrs    = (const float*)d_in[2];
    const float* edge_emb = (const float*)d_in[3];
    const float* edge_sh0 = (const float*)d_in[4];
    const float* edge_sh1 = (const float*)d_in[5];
    const float* W1_s     = (const float*)d_in[6];
    const float* W1_v     = (const float*)d_in[7];
    const float* Wm1      = (const float*)d_in[8];
    const float* Wm2      = (const float*)d_in[9];
    const float* W2_s     = (const float*)d_in[10];
    const float* W2_v     = (const float*)d_in[11];
    const float* Wsc_s    = (const float*)d_in[12];
    const float* Wsc_v    = (const float*)d_in[13];
    const int*   edge_src = (const int*)d_in[14];
    const int*   edge_dst = (const int*)d_in[15];
    float* out = (float*)d_out;

    // workspace layout (unchanged)
    float* x     = (float*)d_ws;                     // N*128
    float* epack = x + (size_t)NN * 128;             // E*16
    int*   counts  = (int*)(epack + (size_t)NE * 16);// N
    int*   offsets = counts + NN;                    // N+1
    int*   cursor  = offsets + NN + 1;               // N
    int*   escan   = cursor + NN;                    // N
    int*   bsum    = escan + NN;                     // SCANB

    hipMemsetAsync(counts, 0, NN * sizeof(int), stream);

    k_node<<<NN / NPB, 256, 0, stream>>>(node_s, node_v, attrs,
                                         W1_s, W1_v, Wsc_s, Wsc_v,
                                         edge_dst, counts, x, out);
    k_scan_a<<<SCANB, 1024, 0, stream>>>(counts, escan, bsum);
    k_scan_c<<<SCANB, 1024, 0, stream>>>(escan, bsum, offsets, cursor);
    k_pack<<<(NE + 255) / 256, 256, 0, stream>>>(edge_emb, edge_sh0, edge_sh1,
                                                 edge_src, edge_dst, Wm1,
                                                 cursor, epack);
    k_gather<<<NN / 4, 256, 0, stream>>>(x, epack, Wm2, W2_s, W2_v,
                                         offsets, out);
}